// Round 6
// baseline (371.817 us; speedup 1.0000x reference)
//
#include <hip/hip_runtime.h>
#include <math.h>

// Problem constants (fixed by reference setup_inputs)
#define TFRAMES 6
#define ZD 32
#define YD 512
#define XD 512
#define NRAYS 65536
#define NSTEPS 192          // 192 = 64 lanes * 3 steps/lane
#define VOXEL 0.2f

// Ray binning: 6 frames x 8x8 endpoint tiles = 384 bins. Rays in the same bin
// start near grid center and end in the same 64x64 (x,y) column -> their
// sampled voxel lines overlap heavily. Running them adjacently shrinks the
// resident working set from 201 MB (all frames, random) to a few MB -> L3/L2
// resident gathers instead of HBM refetch (observed 391 MB FETCH ~= 2x sigma).
#define NBINS (TFRAMES * 64)

// ---- binning kernels (all trivial cost vs the 124us render) ----

__global__ void zero_counts_kernel(int* counts) {
    if (threadIdx.x < NBINS) counts[threadIdx.x] = 0;
}

__device__ __forceinline__ int ray_bin(const float* pcd, const int* tindex, int i) {
    const int   t  = tindex[i];
    const float px = pcd[i * 3 + 0];
    const float py = pcd[i * 3 + 1];
    const int ex = min(7, max(0, (int)(px * (1.0f / 64.0f))));
    const int ey = min(7, max(0, (int)(py * (1.0f / 64.0f))));
    return (t * 8 + ey) * 8 + ex;
}

__global__ __launch_bounds__(256) void hist_kernel(
    const float* __restrict__ pcd, const int* __restrict__ tindex, int* counts) {
    const int i = blockIdx.x * 256 + threadIdx.x;   // grid exactly covers NRAYS
    atomicAdd(&counts[ray_bin(pcd, tindex, i)], 1);
}

__global__ void prefix_kernel(const int* __restrict__ counts, int* offsets) {
    if (threadIdx.x == 0 && blockIdx.x == 0) {
        int acc = 0;
        for (int b = 0; b < NBINS; ++b) { offsets[b] = acc; acc += counts[b]; }
    }
}

__global__ __launch_bounds__(256) void scatter_kernel(
    const float* __restrict__ pcd, const int* __restrict__ tindex,
    int* offsets, int* __restrict__ perm) {
    const int i = blockIdx.x * 256 + threadIdx.x;
    const int pos = atomicAdd(&offsets[ray_bin(pcd, tindex, i)], 1);
    perm[pos] = i;   // bijection: every ray id lands in exactly one slot
}

// ---- render: wave-per-ray, identical per-ray math as before (bit-exact) ----

__global__ __launch_bounds__(256) void volrender_kernel(
    const float* __restrict__ sigma,   // [T,Z,Y,X]
    const float* __restrict__ org,     // [T,3]
    const float* __restrict__ pcd,     // [N,3]
    const int*   __restrict__ tindex,  // [N]
    const int*   __restrict__ perm,    // [N] binned ray order (or null)
    float*       __restrict__ out)     // [2*N]: pred then gt
{
    const int lane = threadIdx.x & 63;
    // XCD-chunk swizzle: 16384 blocks, 8 XCDs, round-robin dispatch ->
    // logical chunk of 2048 consecutive blocks lands on one XCD, so
    // same-bin rays share that XCD's L2/L3 path. Perf heuristic only.
    const int lb   = (blockIdx.x & 7) * 2048 + (blockIdx.x >> 3);
    const int slot = lb * 4 + (threadIdx.x >> 6);
    if (slot >= NRAYS) return;
    const int ray = perm ? perm[slot] : slot;

    // Ray-uniform data (every lane loads same address -> HW broadcast)
    const int   t  = tindex[ray];
    const float px = pcd[ray * 3 + 0];
    const float py = pcd[ray * 3 + 1];
    const float pz = pcd[ray * 3 + 2];
    const float ox = org[t * 3 + 0];
    const float oy = org[t * 3 + 1];
    const float oz = org[t * 3 + 2];

    const float rx = px - ox, ry = py - oy, rz = pz - oz;
    float gt = sqrtf(rx * rx + ry * ry + rz * rz);
    const float invgt = 1.0f / fmaxf(gt, 1e-8f);
    const float dx = rx * invgt, dy = ry * invgt, dz = rz * invgt;
    const float delta = gt * (1.0f / NSTEPS);

    const int base = t * (ZD * YD * XD);

    float tau[3], tt[3];
#pragma unroll
    for (int j = 0; j < 3; ++j) {
        const int   s    = lane * 3 + j;
        const float frac = ((float)s + 0.5f) * (1.0f / NSTEPS);
        const float tcur = gt * frac;
        tt[j] = tcur;
        const float x = ox + dx * tcur;
        const float y = oy + dy * tcur;
        const float z = oz + dz * tcur;
        const int ix = (int)floorf(x);
        const int iy = (int)floorf(y);
        const int iz = (int)floorf(z);
        const bool inside = (ix >= 0) & (ix < XD) & (iy >= 0) & (iy < YD) &
                            (iz >= 0) & (iz < ZD);
        // clamp + always-load keeps the wave convergent (no divergent branch)
        const int ixc = min(max(ix, 0), XD - 1);
        const int iyc = min(max(iy, 0), YD - 1);
        const int izc = min(max(iz, 0), ZD - 1);
        const float sv = sigma[base + (izc * YD + iyc) * XD + ixc];
        tau[j] = inside ? sv * delta : 0.0f;
    }

    // Per-lane local prefix of the 3 taus
    const float p0 = tau[0];
    const float p1 = p0 + tau[1];
    const float p2 = p1 + tau[2];

    // Wave-wide inclusive scan of per-lane totals (p2)
    float incl = p2;
#pragma unroll
    for (int off = 1; off < 64; off <<= 1) {
        const float u = __shfl_up(incl, off);
        if (lane >= off) incl += u;
    }
    const float excl  = incl - p2;           // cum before this lane's steps
    const float total = __shfl(incl, 63);    // full-ray optical thickness

    // trans*alpha*t summed: (exp(-cum_before) - exp(-cum_after)) * t
    const float e0 = __expf(-excl);
    const float e1 = __expf(-(excl + p0));
    const float e2 = __expf(-(excl + p1));
    const float e3 = __expf(-(excl + p2));
    float pr = (e0 - e1) * tt[0] + (e1 - e2) * tt[1] + (e2 - e3) * tt[2];

    // Butterfly reduce across the wave
#pragma unroll
    for (int off = 32; off >= 1; off >>= 1)
        pr += __shfl_xor(pr, off);

    float pred = pr + __expf(-total) * gt;   // residual transmittance -> ray end

    // NaN/Inf cleanup (matches reference wrapper semantics)
    if (isnan(pred) || isinf(pred)) { pred = 0.0f; gt = 0.0f; }

    if (lane == 0) {
        out[ray]         = pred * VOXEL;
        out[NRAYS + ray] = gt * VOXEL;
    }
}

extern "C" void kernel_launch(void* const* d_in, const int* in_sizes, int n_in,
                              void* d_out, int out_size, void* d_ws, size_t ws_size,
                              hipStream_t stream) {
    const float* sigma  = (const float*)d_in[0];  // [1,6,32,512,512]
    const float* org    = (const float*)d_in[1];  // [1,6,3]
    const float* pcd    = (const float*)d_in[2];  // [1,65536,3]
    const int*   tindex = (const int*)d_in[3];    // [1,65536]
    float*       out    = (float*)d_out;          // [2*65536]

    // ws layout: counts[384] | offsets[384] | perm[65536]  (ints)
    const size_t need = (size_t)(NBINS * 2 + NRAYS) * sizeof(int);
    int* perm = nullptr;
    if (d_ws && ws_size >= need) {
        int* counts  = (int*)d_ws;
        int* offsets = counts + NBINS;
        perm         = offsets + NBINS;
        zero_counts_kernel<<<1, NBINS, 0, stream>>>(counts);
        hist_kernel<<<NRAYS / 256, 256, 0, stream>>>(pcd, tindex, counts);
        prefix_kernel<<<1, 64, 0, stream>>>(counts, offsets);
        scatter_kernel<<<NRAYS / 256, 256, 0, stream>>>(pcd, tindex, offsets, perm);
    }

    // one wave (64 lanes) per ray; 256 threads/block = 4 rays/block
    const int threads = 256;
    const int blocks  = (NRAYS * 64) / threads;   // 16384
    volrender_kernel<<<blocks, threads, 0, stream>>>(sigma, org, pcd, tindex, perm, out);
}

// Round 7
// 368.828 us; speedup vs baseline: 1.0081x; 1.0081x over previous
//
#include <hip/hip_runtime.h>
#include <math.h>

// Problem constants (fixed by reference setup_inputs)
#define TFRAMES 6
#define ZD 32
#define YD 512
#define XD 512
#define NRAYS 65536
#define NSTEPS 192          // 192 = 64 lanes * 3 steps/lane
#define VOXEL 0.2f

// Ray binning: 6 frames x 8x8 endpoint tiles = 384 bins. Rays in the same bin
// start near grid center and end in the same 64x64 (x,y) column -> their
// sampled voxel lines overlap heavily. Running them adjacently shrinks the
// resident working set from 201 MB (all frames, random) to a few MB -> L3/L2
// resident gathers instead of HBM refetch (observed 391 MB FETCH ~= 2x sigma
// without binning).
#define NBINS (TFRAMES * 64)

// ---- binning kernels ----

__global__ void zero_counts_kernel(int* counts) {
    if (threadIdx.x < NBINS) counts[threadIdx.x] = 0;
}

__device__ __forceinline__ int ray_bin(const float* pcd, const int* tindex, int i) {
    const int   t  = tindex[i];
    const float px = pcd[i * 3 + 0];
    const float py = pcd[i * 3 + 1];
    const int ex = min(7, max(0, (int)(px * (1.0f / 64.0f))));
    const int ey = min(7, max(0, (int)(py * (1.0f / 64.0f))));
    return (t * 8 + ey) * 8 + ex;
}

__global__ __launch_bounds__(256) void hist_kernel(
    const float* __restrict__ pcd, const int* __restrict__ tindex, int* counts) {
    const int i = blockIdx.x * 256 + threadIdx.x;   // grid exactly covers NRAYS
    atomicAdd(&counts[ray_bin(pcd, tindex, i)], 1);
}

// Parallel exclusive prefix over 384 bins: one block, Hillis-Steele in LDS.
// (R6 lesson: the single-thread version serialized ~384 dependent global
// round-trips and cost more than the render saved.)
__global__ __launch_bounds__(NBINS) void prefix_kernel(
    const int* __restrict__ counts, int* __restrict__ offsets) {
    __shared__ int buf[NBINS];
    const int tid = threadIdx.x;
    const int v = counts[tid];
    buf[tid] = v;
    __syncthreads();
#pragma unroll
    for (int off = 1; off < NBINS; off <<= 1) {
        const int add = (tid >= off) ? buf[tid - off] : 0;
        __syncthreads();
        buf[tid] += add;
        __syncthreads();
    }
    offsets[tid] = buf[tid] - v;   // exclusive prefix
}

__global__ __launch_bounds__(256) void scatter_kernel(
    const float* __restrict__ pcd, const int* __restrict__ tindex,
    int* offsets, int* __restrict__ perm) {
    const int i = blockIdx.x * 256 + threadIdx.x;
    const int pos = atomicAdd(&offsets[ray_bin(pcd, tindex, i)], 1);
    perm[pos] = i;   // bijection: every ray id lands in exactly one slot
}

// ---- render: wave-per-ray, identical per-ray math as R5 (bit-exact) ----

__global__ __launch_bounds__(256) void volrender_kernel(
    const float* __restrict__ sigma,   // [T,Z,Y,X]
    const float* __restrict__ org,     // [T,3]
    const float* __restrict__ pcd,     // [N,3]
    const int*   __restrict__ tindex,  // [N]
    const int*   __restrict__ perm,    // [N] binned ray order (or null)
    float*       __restrict__ out)     // [2*N]: pred then gt
{
    const int lane = threadIdx.x & 63;
    // XCD-chunk swizzle: 16384 blocks, 8 XCDs, round-robin dispatch ->
    // a contiguous range of 2048 logical blocks (same/adjacent bins) lands
    // on one XCD, sharing its L2. Perf heuristic only.
    const int lb   = (blockIdx.x & 7) * 2048 + (blockIdx.x >> 3);
    const int slot = lb * 4 + (threadIdx.x >> 6);
    if (slot >= NRAYS) return;
    const int ray = perm ? perm[slot] : slot;

    // Ray-uniform data (every lane loads same address -> HW broadcast)
    const int   t  = tindex[ray];
    const float px = pcd[ray * 3 + 0];
    const float py = pcd[ray * 3 + 1];
    const float pz = pcd[ray * 3 + 2];
    const float ox = org[t * 3 + 0];
    const float oy = org[t * 3 + 1];
    const float oz = org[t * 3 + 2];

    const float rx = px - ox, ry = py - oy, rz = pz - oz;
    float gt = sqrtf(rx * rx + ry * ry + rz * rz);
    const float invgt = 1.0f / fmaxf(gt, 1e-8f);
    const float dx = rx * invgt, dy = ry * invgt, dz = rz * invgt;
    const float delta = gt * (1.0f / NSTEPS);

    const int base = t * (ZD * YD * XD);

    float tau[3], tt[3];
#pragma unroll
    for (int j = 0; j < 3; ++j) {
        const int   s    = lane * 3 + j;
        const float frac = ((float)s + 0.5f) * (1.0f / NSTEPS);
        const float tcur = gt * frac;
        tt[j] = tcur;
        const float x = ox + dx * tcur;
        const float y = oy + dy * tcur;
        const float z = oz + dz * tcur;
        const int ix = (int)floorf(x);
        const int iy = (int)floorf(y);
        const int iz = (int)floorf(z);
        const bool inside = (ix >= 0) & (ix < XD) & (iy >= 0) & (iy < YD) &
                            (iz >= 0) & (iz < ZD);
        // clamp + always-load keeps the wave convergent (no divergent branch)
        const int ixc = min(max(ix, 0), XD - 1);
        const int iyc = min(max(iy, 0), YD - 1);
        const int izc = min(max(iz, 0), ZD - 1);
        const float sv = sigma[base + (izc * YD + iyc) * XD + ixc];
        tau[j] = inside ? sv * delta : 0.0f;
    }

    // Per-lane local prefix of the 3 taus
    const float p0 = tau[0];
    const float p1 = p0 + tau[1];
    const float p2 = p1 + tau[2];

    // Wave-wide inclusive scan of per-lane totals (p2)
    float incl = p2;
#pragma unroll
    for (int off = 1; off < 64; off <<= 1) {
        const float u = __shfl_up(incl, off);
        if (lane >= off) incl += u;
    }
    const float excl  = incl - p2;           // cum before this lane's steps
    const float total = __shfl(incl, 63);    // full-ray optical thickness

    // trans*alpha*t summed: (exp(-cum_before) - exp(-cum_after)) * t
    const float e0 = __expf(-excl);
    const float e1 = __expf(-(excl + p0));
    const float e2 = __expf(-(excl + p1));
    const float e3 = __expf(-(excl + p2));
    float pr = (e0 - e1) * tt[0] + (e1 - e2) * tt[1] + (e2 - e3) * tt[2];

    // Butterfly reduce across the wave
#pragma unroll
    for (int off = 32; off >= 1; off >>= 1)
        pr += __shfl_xor(pr, off);

    float pred = pr + __expf(-total) * gt;   // residual transmittance -> ray end

    // NaN/Inf cleanup (matches reference wrapper semantics)
    if (isnan(pred) || isinf(pred)) { pred = 0.0f; gt = 0.0f; }

    if (lane == 0) {
        out[ray]         = pred * VOXEL;
        out[NRAYS + ray] = gt * VOXEL;
    }
}

extern "C" void kernel_launch(void* const* d_in, const int* in_sizes, int n_in,
                              void* d_out, int out_size, void* d_ws, size_t ws_size,
                              hipStream_t stream) {
    const float* sigma  = (const float*)d_in[0];  // [1,6,32,512,512]
    const float* org    = (const float*)d_in[1];  // [1,6,3]
    const float* pcd    = (const float*)d_in[2];  // [1,65536,3]
    const int*   tindex = (const int*)d_in[3];    // [1,65536]
    float*       out    = (float*)d_out;          // [2*65536]

    // ws layout: counts[384] | offsets[384] | perm[65536]  (ints)
    const size_t need = (size_t)(NBINS * 2 + NRAYS) * sizeof(int);
    int* perm = nullptr;
    if (d_ws && ws_size >= need) {
        int* counts  = (int*)d_ws;
        int* offsets = counts + NBINS;
        perm         = offsets + NBINS;
        zero_counts_kernel<<<1, NBINS, 0, stream>>>(counts);
        hist_kernel<<<NRAYS / 256, 256, 0, stream>>>(pcd, tindex, counts);
        prefix_kernel<<<1, NBINS, 0, stream>>>(counts, offsets);
        scatter_kernel<<<NRAYS / 256, 256, 0, stream>>>(pcd, tindex, offsets, perm);
    }

    // one wave (64 lanes) per ray; 256 threads/block = 4 rays/block
    const int threads = 256;
    const int blocks  = (NRAYS * 64) / threads;   // 16384
    volrender_kernel<<<blocks, threads, 0, stream>>>(sigma, org, pcd, tindex, perm, out);
}